// Round 10
// baseline (212.463 us; speedup 1.0000x reference)
//
#include <hip/hip_runtime.h>
#include <hip/hip_bf16.h>

// Problem: B=2, S=2048, D_MODEL=1024, H=16, DK=64.
// out = ((l2norm(Q Wq^T) l2norm(K Wk^T)^T)^2 (V Wv^T)) Wo^T   (per head)
// fp32 in/out; internally bf16 MFMA with fp32 accumulation.
//
// Round 18 changes vs round 17 (attn only; qkv/wo/convert kept as measured):
//  - PV upgraded K=16 -> K=32 by PAIRING two k-tiles per compute step.
//    k-slot bijection: K=32 B-frag slot quad*8+e maps to
//    (e<4 ? tileA j=quad*4+e : tileB j=quad*4+(e-4)). The packed
//    {pbA,pbB} s16x8 is then a legal B-frag, and the V A-frag is the two
//    existing b64 reads concatenated (contraction order over j is free).
//    PV MFMA instruction count halves: issue floor ~25 -> ~16.6 us.
//  - 4-deep ring kept; 2 barriers per PAIR (same per-tile barrier count);
//    stage of tiles 2p+4,2p+5 after lgkm-barrier (hazard: their bufs were
//    read by THIS pair's compute -> must drain reads first).

#define D_MODEL 1024
#define N_HEADS 16
#define D_K     64
#define BATCH   2
#define SEQ     2048
#define M_TOT   (BATCH * SEQ)   // 4096

typedef short  s16x8 __attribute__((ext_vector_type(8)));   // 8 bf16 = 4 VGPR
typedef short  s16x4 __attribute__((ext_vector_type(4)));   // 4 bf16 = 2 VGPR
typedef float  f32x4 __attribute__((ext_vector_type(4)));   // MFMA C/D frag
typedef unsigned short ushort_t;
typedef ushort_t us4 __attribute__((ext_vector_type(4)));
typedef ushort_t us8 __attribute__((ext_vector_type(8)));

__device__ __forceinline__ ushort_t f2bf(float f) {
    union { float f; unsigned int u; } x; x.f = f;
    unsigned int u = x.u;
    return (ushort_t)((u + 0x7fffu + ((u >> 16) & 1u)) >> 16);  // RNE
}
__device__ __forceinline__ float bf2f(ushort_t h) {
    union { unsigned int u; float f; } x; x.u = ((unsigned int)h) << 16;
    return x.f;
}
// pack two fp32 -> u32 of two bf16 (RNE)
__device__ __forceinline__ unsigned int pack2bf(float a, float b) {
    union { __hip_bfloat162 h; unsigned int u; } x;
    x.h = __float22bfloat162_rn(float2{a, b});
    return x.u;
}

// async global->LDS, 16B per lane (lane i's lds ptr == wave base + i*16).
__device__ __forceinline__ void gload_lds16(const ushort_t* g, ushort_t* l) {
    __builtin_amdgcn_global_load_lds(
        (__attribute__((address_space(1))) void*)(ushort_t*)g,
        (__attribute__((address_space(3))) void*)l, 16, 0, 0);
}

#define WAIT_VM(n)  asm volatile("s_waitcnt vmcnt(" #n ")" ::: "memory")
#define WAIT_LGKM0  asm volatile("s_waitcnt lgkmcnt(0)" ::: "memory")
#define BARRIER     asm volatile("s_barrier" ::: "memory")

// ---------------------------------------------------------------------------
// fp32 -> bf16 conversion, flattened 1D grid: block -> (tensor, chunk) via
// chunk-prefix table; 2048 elements per block (8 per thread).
// ---------------------------------------------------------------------------
struct ConvArgs {
    const float* src[11];
    ushort_t*    dst[11];
    int          n[11];
    int          cum[12];   // chunk prefix sums
};

__global__ __launch_bounds__(256) void convert_kernel(ConvArgs a) {
    const int lin = blockIdx.x;
    int t = 0;
#pragma unroll
    for (int i = 0; i < 11; ++i)
        if (lin >= a.cum[i + 1]) t = i + 1;
    const int off = (lin - a.cum[t]) * 2048 + threadIdx.x * 8;
    if (off >= a.n[t]) return;
    const float4 v0 = *(const float4*)(a.src[t] + off);
    const float4 v1 = *(const float4*)(a.src[t] + off + 4);
    us8 p;
    p[0] = f2bf(v0.x); p[1] = f2bf(v0.y); p[2] = f2bf(v0.z); p[3] = f2bf(v0.w);
    p[4] = f2bf(v1.x); p[5] = f2bf(v1.y); p[6] = f2bf(v1.z); p[7] = f2bf(v1.w);
    *(us8*)(a.dst[t] + off) = p;
}

// ---------------------------------------------------------------------------
// GEMM body BK=64 (used by wo): BM x 128 tile, 4 waves 2x2, 2-deep DMA
// pipeline, issue-early staging. MODE 0: fp32 store.
// ---------------------------------------------------------------------------
template <int BM>
__device__ __forceinline__ void gemm_body(
    ushort_t* __restrict__ smem,
    const ushort_t* __restrict__ A,
    const ushort_t* __restrict__ W,
    const ushort_t* __restrict__ bias,
    float* __restrict__ outf,
    int bx, int by)
{
    static_assert(BM == 64 || BM == 128, "");
    constexpr int K    = 1024;
    constexpr int MF   = BM / 32;
    constexpr int BUFW = (BM + 128) * 64;
    constexpr int NIT  = K / 64;

    const int t    = threadIdx.x;
    const int wave = t >> 6;
    const int lane = t & 63;
    const int quad = lane >> 4;
    const int lc   = lane & 15;
    const int wm   = wave >> 1;
    const int wn   = wave & 1;
    const int m0   = bx * BM;
    const int n0   = by * 128;

    f32x4 acc[MF][4];
    const f32x4 zero = {0.f, 0.f, 0.f, 0.f};
#pragma unroll
    for (int i = 0; i < MF; ++i)
#pragma unroll
        for (int j = 0; j < 4; ++j) acc[i][j] = zero;

    auto stage = [&](int buf, int k0) {
        ushort_t* Ast = smem + buf * BUFW;
        ushort_t* Bst = Ast + BM * 64;
#pragma unroll
        for (int c = 0; c < MF; ++c) {
            int idx = c * 256 + t;
            int row = idx >> 3, phys = idx & 7;
            int col = (phys ^ (row & 7)) * 8;
            gload_lds16(A + (size_t)(m0 + row) * K + k0 + col, Ast + idx * 8);
        }
#pragma unroll
        for (int c = 0; c < 4; ++c) {
            int idx = c * 256 + t;
            int row = idx >> 3, phys = idx & 7;
            int col = (phys ^ (row & 7)) * 8;
            gload_lds16(W + (size_t)(n0 + row) * K + k0 + col, Bst + idx * 8);
        }
    };
    auto loadfrags = [&](int buf, s16x8 (&a)[MF][2], s16x8 (&b)[4][2]) {
        ushort_t* Ast = smem + buf * BUFW;
        ushort_t* Bst = Ast + BM * 64;
#pragma unroll
        for (int ks = 0; ks < 2; ++ks) {
            const int ph = ((ks * 4 + quad) ^ (lc & 7)) * 8;
#pragma unroll
            for (int i = 0; i < MF; ++i)
                a[i][ks] = *(const s16x8*)(Ast + (wm * (BM / 2) + i * 16 + lc) * 64 + ph);
#pragma unroll
            for (int i = 0; i < 4; ++i)
                b[i][ks] = *(const s16x8*)(Bst + (wn * 64 + i * 16 + lc) * 64 + ph);
        }
    };
    auto mfmas = [&](s16x8 (&a)[MF][2], s16x8 (&b)[4][2]) {
#pragma unroll
        for (int ks = 0; ks < 2; ++ks)
#pragma unroll
            for (int mf = 0; mf < MF; ++mf)
#pragma unroll
                for (int nf = 0; nf < 4; ++nf)
                    acc[mf][nf] = __builtin_amdgcn_mfma_f32_16x16x32_bf16(
                        a[mf][ks], b[nf][ks], acc[mf][nf], 0, 0, 0);
    };

    stage(0, 0);
    stage(1, 64);
    s16x8 afr[MF][2], bfr[4][2];
    for (int it = 0; it < NIT; ++it) {
        if (it < NIT - 1) {
            if constexpr (BM == 128) WAIT_VM(8); else WAIT_VM(6);
        } else {
            WAIT_VM(0);
        }
        BARRIER;                       // tile `it` landed
        loadfrags(it & 1, afr, bfr);
        WAIT_LGKM0;
        BARRIER;                       // all waves' reads done -> buf reusable
        if (it < NIT - 2) stage(it & 1, (it + 2) * 64);   // issue-early DMA
        mfmas(afr, bfr);               // covers the DMA flight
    }

    float bv[4];
#pragma unroll
    for (int nf = 0; nf < 4; ++nf) bv[nf] = bf2f(bias[n0 + wn * 64 + nf * 16 + lc]);

#pragma unroll
    for (int mf = 0; mf < MF; ++mf)
#pragma unroll
        for (int nf = 0; nf < 4; ++nf)
#pragma unroll
            for (int r = 0; r < 4; ++r) {
                int mg = m0 + wm * (BM / 2) + mf * 16 + quad * 4 + r;
                int ng = n0 + wn * 64 + nf * 16 + lc;
                outf[(size_t)mg * D_MODEL + ng] = acc[mf][nf][r] + bv[nf];
            }
}

// ---------------------------------------------------------------------------
// GEMM body BK=32 (used by qkv): 128x128 tile, 4 waves 2x2, 2-deep pipeline,
// 32 K-steps, 16 KB/buf. LDS 32 KB ring (+ MODE2 36 KB overlay) -> 3 blk/CU.
// MODE 1: L2-norm -> (B,H,S,DK)   MODE 2: transpose -> (B,H,DK,S)
// ---------------------------------------------------------------------------
template <int MODE>
__device__ __forceinline__ void gemm_body32(
    ushort_t* __restrict__ smem,
    const ushort_t* __restrict__ A,
    const ushort_t* __restrict__ W,
    const ushort_t* __restrict__ bias,
    ushort_t* __restrict__ out,
    int bx, int by)
{
    constexpr int K    = 1024;
    constexpr int BUFW = 256 * 32;         // 8192 elems = 16 KB per buf
    constexpr int NIT  = K / 32;           // 32

    const int t    = threadIdx.x;
    const int wave = t >> 6;
    const int lane = t & 63;
    const int quad = lane >> 4;
    const int lc   = lane & 15;
    const int wm   = wave >> 1;
    const int wn   = wave & 1;
    const int m0   = bx * 128;
    const int n0   = by * 128;

    f32x4 acc[4][4];
    const f32x4 zero = {0.f, 0.f, 0.f, 0.f};
#pragma unroll
    for (int i = 0; i < 4; ++i)
#pragma unroll
        for (int j = 0; j < 4; ++j) acc[i][j] = zero;

    // rows of 32 elems = 4 chunks of 8; chunk phys holds logical phys^(row&3)
    auto stage = [&](int buf, int k0) {
        ushort_t* Ast = smem + buf * BUFW;
        ushort_t* Bst = Ast + 128 * 32;
#pragma unroll
        for (int c = 0; c < 2; ++c) {
            int idx = c * 256 + t;         // 0..511
            int row = idx >> 2, phys = idx & 3;
            int col = (phys ^ (row & 3)) * 8;
            gload_lds16(A + (size_t)(m0 + row) * K + k0 + col, Ast + idx * 8);
        }
#pragma unroll
        for (int c = 0; c < 2; ++c) {
            int idx = c * 256 + t;
            int row = idx >> 2, phys = idx & 3;
            int col = (phys ^ (row & 3)) * 8;
            gload_lds16(W + (size_t)(n0 + row) * K + k0 + col, Bst + idx * 8);
        }
    };
    auto loadfrags = [&](int buf, s16x8 (&a)[4], s16x8 (&b)[4]) {
        ushort_t* Ast = smem + buf * BUFW;
        ushort_t* Bst = Ast + 128 * 32;
#pragma unroll
        for (int i = 0; i < 4; ++i) {
            int ra = wm * 64 + i * 16 + lc;
            a[i] = *(const s16x8*)(Ast + ra * 32 + ((quad ^ (ra & 3)) * 8));
            int rb = wn * 64 + i * 16 + lc;
            b[i] = *(const s16x8*)(Bst + rb * 32 + ((quad ^ (rb & 3)) * 8));
        }
    };
    auto mfmas = [&](s16x8 (&a)[4], s16x8 (&b)[4]) {
#pragma unroll
        for (int mf = 0; mf < 4; ++mf)
#pragma unroll
            for (int nf = 0; nf < 4; ++nf)
                acc[mf][nf] = __builtin_amdgcn_mfma_f32_16x16x32_bf16(
                    a[mf], b[nf], acc[mf][nf], 0, 0, 0);
    };

    stage(0, 0);
    stage(1, 32);
    s16x8 afr[4], bfr[4];
    for (int it = 0; it < NIT; ++it) {
        if (it < NIT - 1) { WAIT_VM(4); } else { WAIT_VM(0); }
        BARRIER;                       // tile `it` landed
        loadfrags(it & 1, afr, bfr);
        WAIT_LGKM0;
        BARRIER;                       // all waves' reads done -> buf reusable
        if (it < NIT - 2) stage(it & 1, (it + 2) * 32);   // issue-early DMA
        mfmas(afr, bfr);               // covers the DMA flight
    }

    float bv[4];
#pragma unroll
    for (int nf = 0; nf < 4; ++nf) bv[nf] = bf2f(bias[n0 + wn * 64 + nf * 16 + lc]);

    if (MODE == 1) {
#pragma unroll
        for (int mf = 0; mf < 4; ++mf)
#pragma unroll
            for (int r = 0; r < 4; ++r) {
                float ss = 0.f;
#pragma unroll
                for (int nf = 0; nf < 4; ++nf) {
                    float v = acc[mf][nf][r] + bv[nf];
                    acc[mf][nf][r] = v;
                    ss += v * v;
                }
                ss += __shfl_xor(ss, 1);
                ss += __shfl_xor(ss, 2);
                ss += __shfl_xor(ss, 4);
                ss += __shfl_xor(ss, 8);
                float inv = rsqrtf(ss + 1e-8f);
                int mg = m0 + wm * 64 + mf * 16 + quad * 4 + r;
                int b  = mg >> 11;
                int s  = mg & 2047;
#pragma unroll
                for (int nf = 0; nf < 4; ++nf) {
                    int ng = n0 + wn * 64 + nf * 16 + lc;
                    int h = ng >> 6, d = ng & 63;
                    out[(((size_t)(b * N_HEADS + h)) * SEQ + s) * D_K + d] =
                        f2bf(acc[mf][nf][r] * inv);
                }
            }
    } else {
        __syncthreads();
        ushort_t* vt = smem + wave * (64 * 72);   // 4*4608 = 18432 <= smem
#pragma unroll
        for (int mf = 0; mf < 4; ++mf)
#pragma unroll
            for (int nf = 0; nf < 4; ++nf) {
                us4 p;
#pragma unroll
                for (int r = 0; r < 4; ++r) p[r] = f2bf(acc[mf][nf][r] + bv[nf]);
                *(us4*)(vt + (nf * 16 + lc) * 72 + mf * 16 + quad * 4) = p;
            }
        WAIT_LGKM0;
        __syncthreads();
#pragma unroll
        for (int r = 0; r < 8; ++r) {
            int d  = r * 8 + (lane >> 3);
            int so = (lane & 7) * 8;
            uint4 val = *(const uint4*)(vt + d * 72 + so);
            int mg = m0 + wm * 64 + so;
            int b  = mg >> 11;
            int s  = mg & 2047;
            int ng = n0 + wn * 64 + d;
            int h = ng >> 6, dh = ng & 63;
            *(uint4*)(out + (((size_t)(b * N_HEADS + h)) * D_K + dh) * SEQ + s) = val;
        }
    }
}

// qkv: 1-D grid 768 (= 256 CU x 3 blocks, single round); lin%8 = N-panel.
__global__ __launch_bounds__(256, 3) void qkv_kernel(
    const ushort_t* __restrict__ Qb, const ushort_t* __restrict__ Kb,
    const ushort_t* __restrict__ Vb,
    const ushort_t* __restrict__ Wq, const ushort_t* __restrict__ Wk,
    const ushort_t* __restrict__ Wv,
    const ushort_t* __restrict__ bq, const ushort_t* __restrict__ bk,
    const ushort_t* __restrict__ bv,
    ushort_t* __restrict__ qn, ushort_t* __restrict__ kn,
    ushort_t* __restrict__ vT)
{
    __shared__ __align__(16) ushort_t smem[18432];   // 36 KB (ring 32 KB)
    const int lin = blockIdx.x;
    const int by  = lin & 7;
    const int r   = lin >> 3;          // 0..95
    const int bx  = r & 31;
    const int z   = r >> 5;            // 0..2
    if (z == 0)
        gemm_body32<1>(smem, Qb, Wq, bq, qn, bx, by);
    else if (z == 1)
        gemm_body32<1>(smem, Kb, Wk, bk, kn, bx, by);
    else
        gemm_body32<2>(smem, Vb, Wv, bv, vT, bx, by);
}

// wo: 1-D grid 512; lin%8 = N-panel; BM=64 BK=64 (48 KB LDS).
__global__ __launch_bounds__(256) void wo_kernel(
    const ushort_t* __restrict__ A, const ushort_t* __restrict__ W,
    const ushort_t* __restrict__ bias, float* __restrict__ outf)
{
    __shared__ __align__(16) ushort_t smem[2 * (64 + 128) * 64];   // 48 KB
    const int lin = blockIdx.x;
    gemm_body<64>(smem, A, W, bias, outf, lin >> 3, lin & 7);
}

// ---------------------------------------------------------------------------
// Attention: per (b,h): out = (qn kn^T)^2 v.
// Grid (x=bh 32, y=qt 16) -> 512 blocks; bh%8 XCD pin. 128 q/block.
// 64-j k-tiles processed in PAIRS; j-partitioned across waves:
//   wave w owns j-slice [w*16, w*16+16) of each tile.
//   QK^T per tile: S^T = K_slice . Q^T -> f32x4 (lane: j=quad*4+r, q=lc).
//   square+pack both tiles -> s16x8 B-frag of K=32 PV MFMA (k-slot e<4 =
//   tileA j=quad*4+e, e>=4 = tileB j=quad*4+e-4); V A-frag = the two b64
//   reads concatenated. P never touches LDS.
//   PV: O^T[64d][128q] partial per wave (128 VGPR), 4-wave LDS reduction.
// 4-deep staging ring; 2 barriers per pair; counted vmcnt(8).
// ---------------------------------------------------------------------------
__global__ __launch_bounds__(256, 2) void attn_kernel(
    const ushort_t* __restrict__ qn,
    const ushort_t* __restrict__ kn,
    const ushort_t* __restrict__ vT,
    ushort_t* __restrict__ attn_out)
{
    // staging buf i at smem+i*8192: kst [64 j][64 dk] + vst [64 d][64 j]
    // (both 8-el-chunk XOR-swizzled). Epilogue overlays f32 red buf.
    __shared__ __align__(16) ushort_t smem[4 * 8192];   // 64 KB

    const int t    = threadIdx.x;
    const int wave = t >> 6;
    const int lane = t & 63;
    const int quad = lane >> 4;
    const int lc   = lane & 15;
    const int bh   = blockIdx.x;       // 0..31 (bh%8 -> XCD pin)
    const int qt   = blockIdx.y;       // 0..15
    const int b    = bh >> 4;
    const int h    = bh & 15;

    const ushort_t* qb = qn + (size_t)bh * SEQ * D_K;
    const ushort_t* kb = kn + (size_t)bh * SEQ * D_K;
    const ushort_t* vb = vT + (size_t)bh * D_K * SEQ;
    const int q0 = qt * 128;

    // Q B-frags for all 8 q-tiles of this block, reused over 32 k-tiles
    s16x8 qf[8][2];
#pragma unroll
    for (int mf = 0; mf < 8; ++mf)
#pragma unroll
        for (int ks = 0; ks < 2; ++ks)
            qf[mf][ks] = *(const s16x8*)(qb + (size_t)(q0 + mf * 16 + lc) * D_K +
                                         ks * 32 + quad * 8);

    // wave's partial O^T[64 d][128 q]: oacc[df][mf], lane(lc,quad) reg r =
    // O^T[d = df*16 + quad*4 + r][q = mf*16 + lc]
    f32x4 oacc[4][8];
    const f32x4 zero = {0.f, 0.f, 0.f, 0.f};
#pragma unroll
    for (int df = 0; df < 4; ++df)
#pragma unroll
        for (int mf = 0; mf < 8; ++mf) oacc[df][mf] = zero;

    auto stage = [&](int buf, int j0) {
        ushort_t* kst = smem + buf * 8192;
        ushort_t* vst = kst + 4096;
#pragma unroll
        for (int c = 0; c < 2; ++c) {
            int idx = c * 256 + t;
            int row = idx >> 3, phys = idx & 7;
            int col = (phys ^ (row & 7)) * 8;
            gload_lds16(kb + (size_t)(j0 + row) * D_K + col, kst + idx * 8);
            gload_lds16(vb + (size_t)row * SEQ + j0 + col, vst + idx * 8);
        }
    };

    // process a PAIR of tiles (bufs ba, bb): QK^T each, square both,
    // fused K=32 PV.
    auto compute2 = [&](int ba, int bb) {
        ushort_t* kstA = smem + ba * 8192;
        ushort_t* vstA = kstA + 4096;
        ushort_t* kstB = smem + bb * 8192;
        ushort_t* vstB = kstB + 4096;
        // K A-frags for wave's 16-j slice (K=32 over dk), both tiles
        s16x8 akA[2], akB[2];
#pragma unroll
        for (int ks = 0; ks < 2; ++ks) {
            const int off = (wave * 16 + lc) * 64 + (((ks * 4 + quad) ^ (lc & 7)) * 8);
            akA[ks] = *(const s16x8*)(kstA + off);
            akB[ks] = *(const s16x8*)(kstB + off);
        }
        // V^T A-frags for K=32 PV: lane(lc,quad) k-slots quad*8+e:
        //   e=0..3 -> tileA j=wave*16+quad*4+e, e=4..7 -> tileB same j.
        s16x8 av[4];
#pragma unroll
        for (int df = 0; df < 4; ++df) {
            const int d  = df * 16 + lc;
            const int cj = wave * 2 + (quad >> 1);        // logical 8-el chunk
            const int o  = d * 64 + ((cj ^ (d & 7)) << 3) + ((quad & 1) << 2);
            s16x4 lo = *(const s16x4*)(vstA + o);
            s16x4 hi = *(const s16x4*)(vstB + o);
            av[df] = s16x8{lo[0], lo[1], lo[2], lo[3], hi[0], hi[1], hi[2], hi[3]};
        }
#pragma unroll
        for (int mf = 0; mf < 8; ++mf) {
            f32x4 stA = zero, stB = zero;   // S^T: lane = [j=quad*4+r][q=lc]
#pragma unroll
            for (int ks = 0; ks < 2; ++ks) {
                stA = __builtin_amdgcn_mfma_f32_16x16x32_bf16(akA[ks], qf[mf][ks],
                                                              stA, 0, 0, 0);
                stB = __builtin_amdgcn_mfma_f32_16x16x32_bf16(akB[ks], qf[mf][ks],
                                                              stB, 0, 0, 0);
            }
            // square + pack both tiles -> K=32 B-frag (k-slot mapping above)
            union { unsigned int u[4]; s16x8 v; } pb;
            pb.u[0] = pack2bf(stA[0] * stA[0], stA[1] * stA[1]);
            pb.u[1] = pack2bf(stA[2] * stA[2], stA[3] * stA[3]);
            pb.u[2] = pack2bf(stB[0] * stB[0], stB[1] * stB[1]);
            pb.u[3] = pack2bf(stB[2] * stB[2], stB[3] * stB[3]);
#pragma unroll
            for (int df = 0; df < 4; ++df)
                oacc[df][mf] = __builtin_amdgcn_mfma_f32_16x16x32_bf16(
                    av[df], pb.v, oacc[df][mf], 0, 0, 0);
        }
    };

    constexpr int NP = 16;                 // 32 tiles / 2
    stage(0, 0);
    stage(1, 64);
    stage(2, 128);
    stage(3, 192);
    for (int p = 0; p < NP; ++p) {
        if (p < NP - 1) { WAIT_VM(8); } else { WAIT_VM(0); }
        BARRIER;                       // tiles 2p,2p+1 landed everywhere
        compute2((2 * p) & 3, (2 * p + 1) & 3);
        if (p < NP - 2) {
            WAIT_LGKM0;
            BARRIER;                   // all reads of this pair's bufs done
            stage((2 * p) & 3, (2 * p + 4) * 64);
            stage((2 * p + 1) & 3, (2 * p + 5) * 64);
        }
    }

    // 4-wave reduction of O^T partials + store, 8 chunks of 16 q.
    // red[w][d][q], q-pitch 17 to break 4-way write aliasing. 17.4 KB.
    float* red = (float*)smem;
    constexpr int RP = 17;
#pragma unroll
    for (int mf = 0; mf < 8; ++mf) {
        BARRIER;                       // previous chunk's reads (or loop) done
#pragma unroll
        for (int df = 0; df < 4; ++df)
#pragma unroll
            for (int r = 0; r < 4; ++r)
                red[(wave * 64 + df * 16 + quad * 4 + r) * RP + lc] =
                    oacc[df][mf][r];
        WAIT_LGKM0;
        BARRIER;                       // all partials visible
#pragma unroll
        for (int qq = 0; qq < 4; ++qq) {
            const int q = wave * 4 + qq;
            const int d = lane;
            float v = red[(0 * 64 + d) * RP + q] + red[(1 * 64 + d) * RP + q] +
                      red[(2 * 64 + d) * RP + q] + red[(3 * 64 + d) * RP + q];
            const int s = q0 + mf * 16 + q;
            attn_out[((size_t)(b * SEQ + s)) * D_MODEL + h * D_K + d] = f2bf(v);
        }
    }
}

extern "C" void kernel_launch(void* const* d_in, const int* in_sizes, int n_in,
                              void* d_out, int out_size, void* d_ws, size_t ws_size,
                              hipStream_t stream)
{
    const float* Qf   = (const float*)d_in[0];
    const float* Kf   = (const float*)d_in[1];
    const float* Vf   = (const float*)d_in[2];
    const float* Wqf  = (const float*)d_in[3];
    const float* Wqbf = (const float*)d_in[4];
    const float* Wkf  = (const float*)d_in[5];
    const float* Wkbf = (const float*)d_in[6];
    const float* Wvf  = (const float*)d_in[7];
    const float* Wvbf = (const float*)d_in[8];
    const float* Wof  = (const float*)d_in[9];
    const float* Wobf = (const float*)d_in[10];

    const size_t NM = (size_t)M_TOT * D_MODEL;
    const size_t NW = (size_t)D_MODEL * D_MODEL;
    const size_t NB = D_MODEL;

    ushort_t* p = (ushort_t*)d_ws;
    ushort_t* Qb  = p;  p += NM;
    ushort_t* Kb  = p;  p += NM;
    ushort_t* Vb  = p;  p += NM;
    ushort_t* Wq  = p;  p += NW;
    ushort_t* Wk  = p;  p += NW;
    ushort_t* Wv  = p;  p += NW;
    ushort_t* Wo  = p;  p += NW;
    ushort_t* bq  = p;  p += NB;
    ushort_t* bk  = p;  p += NB;
    ushort_t* bvv = p;  p += NB;
    ushort_t* bo  = p;  p += NB;
    ushort_t* qn  = p;  p += NM;   // (B,H,S,DK)
    ushort_t* kn  = p;  p += NM;   // (B,H,S,DK)
    ushort_t* vT  = p;  p += NM;   // (B,H,DK,S)
    ushort_t* ao  = p;  p += NM;   // (B,S,D)

    ConvArgs ca;
    ca.src[0] = Qf;   ca.dst[0] = Qb;  ca.n[0] = (int)NM;
    ca.src[1] = Kf;   ca.dst[1] = Kb;  ca.n[1] = (int)NM;
    ca.src[2] = Vf;   ca.dst[2] = Vb;  ca.n[2] = (int)NM;
    ca.src[3] = Wqf;  ca.dst[3] = Wq;  ca.n[3] = (int)NW;
    ca.src[4] = Wkf;  ca.dst[4] = Wk;  ca.n[4] = (int)NW;
    ca.src[5] = Wvf;  ca.dst[5] = Wv;  ca.n[5] = (int)NW;
    ca.src[6] = Wof;  ca.dst[6] = Wo;  ca.n[6] = (int)NW;
    ca.src[7] = Wqbf; ca.dst[7] = bq;  ca.n[7] = (int)NB;
    ca.src[8] = Wkbf; ca.dst[8] = bk;  ca.n[8] = (int)NB;
    ca.src[9] = Wvbf; ca.dst[9] = bvv; ca.n[9] = (int)NB;
    ca.src[10] = Wobf; ca.dst[10] = bo; ca.n[10] = (int)NB;

    int cum = 0;
    ca.cum[0] = 0;
    for (int i = 0; i < 11; ++i) {
        cum += (ca.n[i] + 2047) / 2048;
        ca.cum[i + 1] = cum;
    }

    dim3 blk(256);
    convert_kernel<<<dim3((unsigned)cum), blk, 0, stream>>>(ca);

    qkv_kernel<<<dim3(768), blk, 0, stream>>>(
        Qb, Kb, Vb, Wq, Wk, Wv, bq, bk, bvv, qn, kn, vT);
    attn_kernel<<<dim3(BATCH * N_HEADS, SEQ / 128), blk, 0, stream>>>(qn, kn, vT, ao);
    wo_kernel<<<dim3(512), blk, 0, stream>>>(
        ao, Wo, bo, (float*)d_out);
}

// Round 11
// 211.242 us; speedup vs baseline: 1.0058x; 1.0058x over previous
//
#include <hip/hip_runtime.h>
#include <hip/hip_bf16.h>

// Problem: B=2, S=2048, D_MODEL=1024, H=16, DK=64.
// out = ((l2norm(Q Wq^T) l2norm(K Wk^T)^T)^2 (V Wv^T)) Wo^T   (per head)
// fp32 in/out; internally bf16 MFMA with fp32 accumulation.
//
// Round 19 changes vs round 18 (attn/wo untouched):
//  - qkv reads Q/K/V DIRECTLY as fp32 (conversion fused into staging),
//    deleting the 75 MB Q/K/V portion of convert_kernel. R16's 3x failure
//    is root-caused and fixed by GRID MAPPING: xcd = lin&7 owns 12
//    contiguous (z,bx) A-tiles; its 8 by-blocks share each 512 KB A-tile
//    in L2 -> A fetched from HBM once (R16: every XCD read all 48 MB).
//  - Pipeline on the R17 BK=32 skeleton: A reg-staged (4x dwordx4 ->
//    cvt -> 2x ds_write_b128, 1-iter lead), W via global_load_lds with a
//    3-deep W ring (2-iter lead, which R16 lacked). 1 barrier/iter.
//    LDS 40 KB -> 3 blocks/CU kept; grid 768 single-round kept.
//    vmcnt ledger (steady): [W(it+1):2, A(it+1):4, W(it+2):2] -> vmcnt(2).
//  - convert_kernel: weights + biases only (8 tensors).

#define D_MODEL 1024
#define N_HEADS 16
#define D_K     64
#define BATCH   2
#define SEQ     2048
#define M_TOT   (BATCH * SEQ)   // 4096

typedef short  s16x8 __attribute__((ext_vector_type(8)));   // 8 bf16 = 4 VGPR
typedef short  s16x4 __attribute__((ext_vector_type(4)));   // 4 bf16 = 2 VGPR
typedef float  f32x4 __attribute__((ext_vector_type(4)));   // MFMA C/D frag
typedef unsigned short ushort_t;
typedef ushort_t us4 __attribute__((ext_vector_type(4)));
typedef ushort_t us8 __attribute__((ext_vector_type(8)));

__device__ __forceinline__ ushort_t f2bf(float f) {
    union { float f; unsigned int u; } x; x.f = f;
    unsigned int u = x.u;
    return (ushort_t)((u + 0x7fffu + ((u >> 16) & 1u)) >> 16);  // RNE
}
__device__ __forceinline__ float bf2f(ushort_t h) {
    union { unsigned int u; float f; } x; x.u = ((unsigned int)h) << 16;
    return x.f;
}
// pack two fp32 -> u32 of two bf16 (RNE)
__device__ __forceinline__ unsigned int pack2bf(float a, float b) {
    union { __hip_bfloat162 h; unsigned int u; } x;
    x.h = __float22bfloat162_rn(float2{a, b});
    return x.u;
}

// async global->LDS, 16B per lane (lane i's lds ptr == wave base + i*16).
__device__ __forceinline__ void gload_lds16(const ushort_t* g, ushort_t* l) {
    __builtin_amdgcn_global_load_lds(
        (__attribute__((address_space(1))) void*)(ushort_t*)g,
        (__attribute__((address_space(3))) void*)l, 16, 0, 0);
}

#define WAIT_VM(n)  asm volatile("s_waitcnt vmcnt(" #n ")" ::: "memory")
#define WAIT_LGKM0  asm volatile("s_waitcnt lgkmcnt(0)" ::: "memory")
#define BARRIER     asm volatile("s_barrier" ::: "memory")

// ---------------------------------------------------------------------------
// fp32 -> bf16 conversion: weights + biases only (8 tensors).
// ---------------------------------------------------------------------------
struct ConvArgs {
    const float* src[8];
    ushort_t*    dst[8];
    int          n[8];
    int          cum[9];   // chunk prefix sums (2048-elem chunks)
};

__global__ __launch_bounds__(256) void convert_kernel(ConvArgs a) {
    const int lin = blockIdx.x;
    int t = 0;
#pragma unroll
    for (int i = 0; i < 8; ++i)
        if (lin >= a.cum[i + 1]) t = i + 1;
    const int off = (lin - a.cum[t]) * 2048 + threadIdx.x * 8;
    if (off >= a.n[t]) return;
    const float4 v0 = *(const float4*)(a.src[t] + off);
    const float4 v1 = *(const float4*)(a.src[t] + off + 4);
    us8 p;
    p[0] = f2bf(v0.x); p[1] = f2bf(v0.y); p[2] = f2bf(v0.z); p[3] = f2bf(v0.w);
    p[4] = f2bf(v1.x); p[5] = f2bf(v1.y); p[6] = f2bf(v1.z); p[7] = f2bf(v1.w);
    *(us8*)(a.dst[t] + off) = p;
}

// ---------------------------------------------------------------------------
// GEMM body BK=64 (used by wo): BM x 128 tile, 4 waves 2x2, 2-deep DMA
// pipeline, issue-early staging. fp32 store.
// ---------------------------------------------------------------------------
template <int BM>
__device__ __forceinline__ void gemm_body(
    ushort_t* __restrict__ smem,
    const ushort_t* __restrict__ A,
    const ushort_t* __restrict__ W,
    const ushort_t* __restrict__ bias,
    float* __restrict__ outf,
    int bx, int by)
{
    static_assert(BM == 64 || BM == 128, "");
    constexpr int K    = 1024;
    constexpr int MF   = BM / 32;
    constexpr int BUFW = (BM + 128) * 64;
    constexpr int NIT  = K / 64;

    const int t    = threadIdx.x;
    const int wave = t >> 6;
    const int lane = t & 63;
    const int quad = lane >> 4;
    const int lc   = lane & 15;
    const int wm   = wave >> 1;
    const int wn   = wave & 1;
    const int m0   = bx * BM;
    const int n0   = by * 128;

    f32x4 acc[MF][4];
    const f32x4 zero = {0.f, 0.f, 0.f, 0.f};
#pragma unroll
    for (int i = 0; i < MF; ++i)
#pragma unroll
        for (int j = 0; j < 4; ++j) acc[i][j] = zero;

    auto stage = [&](int buf, int k0) {
        ushort_t* Ast = smem + buf * BUFW;
        ushort_t* Bst = Ast + BM * 64;
#pragma unroll
        for (int c = 0; c < MF; ++c) {
            int idx = c * 256 + t;
            int row = idx >> 3, phys = idx & 7;
            int col = (phys ^ (row & 7)) * 8;
            gload_lds16(A + (size_t)(m0 + row) * K + k0 + col, Ast + idx * 8);
        }
#pragma unroll
        for (int c = 0; c < 4; ++c) {
            int idx = c * 256 + t;
            int row = idx >> 3, phys = idx & 7;
            int col = (phys ^ (row & 7)) * 8;
            gload_lds16(W + (size_t)(n0 + row) * K + k0 + col, Bst + idx * 8);
        }
    };
    auto loadfrags = [&](int buf, s16x8 (&a)[MF][2], s16x8 (&b)[4][2]) {
        ushort_t* Ast = smem + buf * BUFW;
        ushort_t* Bst = Ast + BM * 64;
#pragma unroll
        for (int ks = 0; ks < 2; ++ks) {
            const int ph = ((ks * 4 + quad) ^ (lc & 7)) * 8;
#pragma unroll
            for (int i = 0; i < MF; ++i)
                a[i][ks] = *(const s16x8*)(Ast + (wm * (BM / 2) + i * 16 + lc) * 64 + ph);
#pragma unroll
            for (int i = 0; i < 4; ++i)
                b[i][ks] = *(const s16x8*)(Bst + (wn * 64 + i * 16 + lc) * 64 + ph);
        }
    };
    auto mfmas = [&](s16x8 (&a)[MF][2], s16x8 (&b)[4][2]) {
#pragma unroll
        for (int ks = 0; ks < 2; ++ks)
#pragma unroll
            for (int mf = 0; mf < MF; ++mf)
#pragma unroll
                for (int nf = 0; nf < 4; ++nf)
                    acc[mf][nf] = __builtin_amdgcn_mfma_f32_16x16x32_bf16(
                        a[mf][ks], b[nf][ks], acc[mf][nf], 0, 0, 0);
    };

    stage(0, 0);
    stage(1, 64);
    s16x8 afr[MF][2], bfr[4][2];
    for (int it = 0; it < NIT; ++it) {
        if (it < NIT - 1) {
            if constexpr (BM == 128) WAIT_VM(8); else WAIT_VM(6);
        } else {
            WAIT_VM(0);
        }
        BARRIER;                       // tile `it` landed
        loadfrags(it & 1, afr, bfr);
        WAIT_LGKM0;
        BARRIER;                       // all waves' reads done -> buf reusable
        if (it < NIT - 2) stage(it & 1, (it + 2) * 64);   // issue-early DMA
        mfmas(afr, bfr);               // covers the DMA flight
    }

    float bv[4];
#pragma unroll
    for (int nf = 0; nf < 4; ++nf) bv[nf] = bf2f(bias[n0 + wn * 64 + nf * 16 + lc]);

#pragma unroll
    for (int mf = 0; mf < MF; ++mf)
#pragma unroll
        for (int nf = 0; nf < 4; ++nf)
#pragma unroll
            for (int r = 0; r < 4; ++r) {
                int mg = m0 + wm * (BM / 2) + mf * 16 + quad * 4 + r;
                int ng = n0 + wn * 64 + nf * 16 + lc;
                outf[(size_t)mg * D_MODEL + ng] = acc[mf][nf][r] + bv[nf];
            }
}

// ---------------------------------------------------------------------------
// Fused GEMM body BK=32 for qkv, fp32 A (conversion in staging).
// LDS: Abuf 2 x 8 KB (smem+buf*4096) + Wbuf 3 x 8 KB (smem+8192+buf*4096)
// = 40 KB -> 3 blocks/CU. A: 4x global_load_dwordx4 -> cvt -> 2x
// ds_write_b128 (1-iter lead). W: gload_lds16, 3-deep ring (2-iter lead).
// Steady vmcnt ledger at top of iter: [W(it+1):2, A(it+1):4, W(it+2):2].
// MODE 1: L2-norm -> (B,H,S,DK)   MODE 2: transpose -> (B,H,DK,S)
// ---------------------------------------------------------------------------
template <int MODE>
__device__ __forceinline__ void gemm_body32f(
    ushort_t* __restrict__ smem,
    const float* __restrict__ Af,
    const ushort_t* __restrict__ W,
    const ushort_t* __restrict__ bias,
    ushort_t* __restrict__ out,
    int bx, int by)
{
    constexpr int K   = 1024;
    constexpr int NIT = K / 32;            // 32

    const int t    = threadIdx.x;
    const int wave = t >> 6;
    const int lane = t & 63;
    const int quad = lane >> 4;
    const int lc   = lane & 15;
    const int wm   = wave >> 1;
    const int wn   = wave & 1;
    const int m0   = bx * 128;
    const int n0   = by * 128;

    f32x4 acc[4][4];
    const f32x4 zero = {0.f, 0.f, 0.f, 0.f};
#pragma unroll
    for (int i = 0; i < 4; ++i)
#pragma unroll
        for (int j = 0; j < 4; ++j) acc[i][j] = zero;

    float4 ar[4];                          // in-flight fp32 A regs (16 VGPR)
    auto loadA = [&](int k0) {
#pragma unroll
        for (int c = 0; c < 2; ++c) {
            int idx = c * 256 + t;
            int row = idx >> 2, phys = idx & 3;
            int col = (phys ^ (row & 3)) * 8;
            const float* src = Af + (size_t)(m0 + row) * K + k0 + col;
            ar[c * 2]     = *(const float4*)(src);
            ar[c * 2 + 1] = *(const float4*)(src + 4);
        }
    };
    auto writeA = [&](int abuf) {
        ushort_t* Ast = smem + abuf * 4096;
#pragma unroll
        for (int c = 0; c < 2; ++c) {
            int idx = c * 256 + t;
            us8 p;
            p[0] = f2bf(ar[c * 2].x);     p[1] = f2bf(ar[c * 2].y);
            p[2] = f2bf(ar[c * 2].z);     p[3] = f2bf(ar[c * 2].w);
            p[4] = f2bf(ar[c * 2 + 1].x); p[5] = f2bf(ar[c * 2 + 1].y);
            p[6] = f2bf(ar[c * 2 + 1].z); p[7] = f2bf(ar[c * 2 + 1].w);
            *(us8*)(Ast + idx * 8) = p;
        }
    };
    auto stageW = [&](int wbuf, int k0) {
        ushort_t* Wst = smem + 8192 + wbuf * 4096;
#pragma unroll
        for (int c = 0; c < 2; ++c) {
            int idx = c * 256 + t;
            int row = idx >> 2, phys = idx & 3;
            int col = (phys ^ (row & 3)) * 8;
            gload_lds16(W + (size_t)(n0 + row) * K + k0 + col, Wst + idx * 8);
        }
    };
    auto loadfrags = [&](int abuf, int wbuf, s16x8 (&a)[4], s16x8 (&b)[4]) {
        ushort_t* Ast = smem + abuf * 4096;
        ushort_t* Wst = smem + 8192 + wbuf * 4096;
#pragma unroll
        for (int i = 0; i < 4; ++i) {
            int ra = wm * 64 + i * 16 + lc;
            a[i] = *(const s16x8*)(Ast + ra * 32 + ((quad ^ (ra & 3)) * 8));
            int rb = wn * 64 + i * 16 + lc;
            b[i] = *(const s16x8*)(Wst + rb * 32 + ((quad ^ (rb & 3)) * 8));
        }
    };
    auto mfmas = [&](s16x8 (&a)[4], s16x8 (&b)[4]) {
#pragma unroll
        for (int mf = 0; mf < 4; ++mf)
#pragma unroll
            for (int nf = 0; nf < 4; ++nf)
                acc[mf][nf] = __builtin_amdgcn_mfma_f32_16x16x32_bf16(
                    a[mf], b[nf], acc[mf][nf], 0, 0, 0);
    };

    // prologue: queue after = [W1:2, A1:4, W2:2]; tile0 ready in LDS.
    loadA(0);                              // A0:4
    stageW(0, 0);                          // W0:2
    stageW(1, 32);                         // W1:2
    WAIT_VM(4);                            // A0 regs landed
    writeA(0);
    loadA(32);                             // A1:4
    stageW(2, 64);                         // W2:2  queue: W0,W1,A1,W2 = 10
    WAIT_VM(8);                            // W0 landed
    WAIT_LGKM0;                            // A0 ds_writes visible
    BARRIER;                               // tile0 ready everywhere

    s16x8 afr[4], bfr[4];
    for (int it = 0; it < NIT; ++it) {
        loadfrags(it & 1, it % 3, afr, bfr);   // ds_read tile it
        if (it < NIT - 1) {
            if (it < NIT - 2) { WAIT_VM(2); }  // drain W(it+1)+A(it+1)
            else              { WAIT_VM(0); }  // tail: only [W,A](NIT-1) left
            writeA((it + 1) & 1);
        }
        WAIT_LGKM0;                        // frag reads + A writes drained
        BARRIER;                           // tile it+1 ready; tile it bufs free
        if (it < NIT - 2) loadA((it + 2) * 32);
        if (it < NIT - 3) stageW((it + 3) % 3, (it + 3) * 32);
        mfmas(afr, bfr);                   // covers the DMA flight
    }

    float bv[4];
#pragma unroll
    for (int nf = 0; nf < 4; ++nf) bv[nf] = bf2f(bias[n0 + wn * 64 + nf * 16 + lc]);

    if (MODE == 1) {
#pragma unroll
        for (int mf = 0; mf < 4; ++mf)
#pragma unroll
            for (int r = 0; r < 4; ++r) {
                float ss = 0.f;
#pragma unroll
                for (int nf = 0; nf < 4; ++nf) {
                    float v = acc[mf][nf][r] + bv[nf];
                    acc[mf][nf][r] = v;
                    ss += v * v;
                }
                ss += __shfl_xor(ss, 1);
                ss += __shfl_xor(ss, 2);
                ss += __shfl_xor(ss, 4);
                ss += __shfl_xor(ss, 8);
                float inv = rsqrtf(ss + 1e-8f);
                int mg = m0 + wm * 64 + mf * 16 + quad * 4 + r;
                int b  = mg >> 11;
                int s  = mg & 2047;
#pragma unroll
                for (int nf = 0; nf < 4; ++nf) {
                    int ng = n0 + wn * 64 + nf * 16 + lc;
                    int h = ng >> 6, d = ng & 63;
                    out[(((size_t)(b * N_HEADS + h)) * SEQ + s) * D_K + d] =
                        f2bf(acc[mf][nf][r] * inv);
                }
            }
    } else {
        __syncthreads();
        ushort_t* vt = smem + wave * (64 * 72);   // 18432 <= 20480 elems
#pragma unroll
        for (int mf = 0; mf < 4; ++mf)
#pragma unroll
            for (int nf = 0; nf < 4; ++nf) {
                us4 p;
#pragma unroll
                for (int r = 0; r < 4; ++r) p[r] = f2bf(acc[mf][nf][r] + bv[nf]);
                *(us4*)(vt + (nf * 16 + lc) * 72 + mf * 16 + quad * 4) = p;
            }
        WAIT_LGKM0;
        __syncthreads();
#pragma unroll
        for (int r = 0; r < 8; ++r) {
            int d  = r * 8 + (lane >> 3);
            int so = (lane & 7) * 8;
            uint4 val = *(const uint4*)(vt + d * 72 + so);
            int mg = m0 + wm * 64 + so;
            int b  = mg >> 11;
            int s  = mg & 2047;
            int ng = n0 + wn * 64 + d;
            int h = ng >> 6, dh = ng & 63;
            *(uint4*)(out + (((size_t)(b * N_HEADS + h)) * D_K + dh) * SEQ + s) = val;
        }
    }
}

// qkv: 1-D grid 768 = 256 CU x 3, single round. XCD mapping: xcd = lin&7
// owns 12 contiguous (z,bx) A-tiles; its 8 by-blocks share each A-tile
// in its L2 -> fp32 A fetched from HBM once.
__global__ __launch_bounds__(256, 3) void qkv_kernel(
    const float* __restrict__ Qf, const float* __restrict__ Kf,
    const float* __restrict__ Vf,
    const ushort_t* __restrict__ Wq, const ushort_t* __restrict__ Wk,
    const ushort_t* __restrict__ Wv,
    const ushort_t* __restrict__ bq, const ushort_t* __restrict__ bk,
    const ushort_t* __restrict__ bv,
    ushort_t* __restrict__ qn, ushort_t* __restrict__ kn,
    ushort_t* __restrict__ vT)
{
    __shared__ __align__(16) ushort_t smem[20480];   // 40 KB
    const int lin = blockIdx.x;
    const int xcd = lin & 7;
    const int idx = lin >> 3;          // 0..95
    const int zbx = xcd * 12 + (idx % 12);   // 0..95, contiguous per XCD
    const int by  = idx / 12;          // 0..7
    const int z   = zbx >> 5;          // 0..2
    const int bx  = zbx & 31;
    if (z == 0)
        gemm_body32f<1>(smem, Qf, Wq, bq, qn, bx, by);
    else if (z == 1)
        gemm_body32f<1>(smem, Kf, Wk, bk, kn, bx, by);
    else
        gemm_body32f<2>(smem, Vf, Wv, bv, vT, bx, by);
}

// wo: 1-D grid 512; lin%8 = N-panel; BM=64 BK=64 (48 KB LDS).
__global__ __launch_bounds__(256) void wo_kernel(
    const ushort_t* __restrict__ A, const ushort_t* __restrict__ W,
    const ushort_t* __restrict__ bias, float* __restrict__ outf)
{
    __shared__ __align__(16) ushort_t smem[2 * (64 + 128) * 64];   // 48 KB
    const int lin = blockIdx.x;
    gemm_body<64>(smem, A, W, bias, outf, lin >> 3, lin & 7);
}

// ---------------------------------------------------------------------------
// Attention (unchanged from R18): per (b,h): out = (qn kn^T)^2 v.
// Grid (x=bh 32, y=qt 16) -> 512 blocks; bh%8 XCD pin. 128 q/block.
// Tile PAIRS with K=32 PV (squared S^T D-frags packed as B-frag).
// ---------------------------------------------------------------------------
__global__ __launch_bounds__(256, 2) void attn_kernel(
    const ushort_t* __restrict__ qn,
    const ushort_t* __restrict__ kn,
    const ushort_t* __restrict__ vT,
    ushort_t* __restrict__ attn_out)
{
    __shared__ __align__(16) ushort_t smem[4 * 8192];   // 64 KB

    const int t    = threadIdx.x;
    const int wave = t >> 6;
    const int lane = t & 63;
    const int quad = lane >> 4;
    const int lc   = lane & 15;
    const int bh   = blockIdx.x;       // 0..31 (bh%8 -> XCD pin)
    const int qt   = blockIdx.y;       // 0..15
    const int b    = bh >> 4;
    const int h    = bh & 15;

    const ushort_t* qb = qn + (size_t)bh * SEQ * D_K;
    const ushort_t* kb = kn + (size_t)bh * SEQ * D_K;
    const ushort_t* vb = vT + (size_t)bh * D_K * SEQ;
    const int q0 = qt * 128;

    s16x8 qf[8][2];
#pragma unroll
    for (int mf = 0; mf < 8; ++mf)
#pragma unroll
        for (int ks = 0; ks < 2; ++ks)
            qf[mf][ks] = *(const s16x8*)(qb + (size_t)(q0 + mf * 16 + lc) * D_K +
                                         ks * 32 + quad * 8);

    f32x4 oacc[4][8];
    const f32x4 zero = {0.f, 0.f, 0.f, 0.f};
#pragma unroll
    for (int df = 0; df < 4; ++df)
#pragma unroll
        for (int mf = 0; mf < 8; ++mf) oacc[df][mf] = zero;

    auto stage = [&](int buf, int j0) {
        ushort_t* kst = smem + buf * 8192;
        ushort_t* vst = kst + 4096;
#pragma unroll
        for (int c = 0; c < 2; ++c) {
            int idx = c * 256 + t;
            int row = idx >> 3, phys = idx & 7;
            int col = (phys ^ (row & 7)) * 8;
            gload_lds16(kb + (size_t)(j0 + row) * D_K + col, kst + idx * 8);
            gload_lds16(vb + (size_t)row * SEQ + j0 + col, vst + idx * 8);
        }
    };

    auto compute2 = [&](int ba, int bb) {
        ushort_t* kstA = smem + ba * 8192;
        ushort_t* vstA = kstA + 4096;
        ushort_t* kstB = smem + bb * 8192;
        ushort_t* vstB = kstB + 4096;
        s16x8 akA[2], akB[2];
#pragma unroll
        for (int ks = 0; ks < 2; ++ks) {
            const int off = (wave * 16 + lc) * 64 + (((ks * 4 + quad) ^ (lc & 7)) * 8);
            akA[ks] = *(const s16x8*)(kstA + off);
            akB[ks] = *(const s16x8*)(kstB + off);
        }
        s16x8 av[4];
#pragma unroll
        for (int df = 0; df < 4; ++df) {
            const int d  = df * 16 + lc;
            const int cj = wave * 2 + (quad >> 1);        // logical 8-el chunk
            const int o  = d * 64 + ((cj ^ (d & 7)) << 3) + ((quad & 1) << 2);
            s16x4 lo = *(const s16x4*)(vstA + o);
            s16x4 hi = *(const s16x4*)(vstB + o);
            av[df] = s16x8{lo[0], lo[1], lo[2], lo[3], hi[0], hi[1], hi[2], hi[3]};
        }
#pragma unroll
        for (int mf = 0; mf < 8; ++mf) {
            f32x4 stA = zero, stB = zero;   // S^T: lane = [j=quad*4+r][q=lc]
#pragma unroll
            for (int ks = 0; ks < 2; ++ks) {
                stA = __builtin_amdgcn_mfma_f32_16x16x32_bf16(akA[ks], qf[mf][ks],
                                                              stA, 0, 0, 0);
                stB = __builtin_amdgcn_mfma_f32_16x16x32_bf16(akB[ks], qf[mf][ks],
                                                              stB, 0, 0, 0);
            }
            union { unsigned int u[4]; s16x8 v; } pb;
            pb.u[0] = pack2bf(stA[0] * stA[0], stA[1] * stA[1]);
            pb.u[1] = pack2bf(stA[2] * stA[2], stA[3] * stA[3]);
            pb.u[2] = pack2bf(stB[0] * stB[0], stB[1] * stB[1]);
            pb.u[3] = pack2bf(stB[2] * stB[2], stB[3] * stB[3]);
#pragma unroll
            for (int df = 0; df < 4; ++df)
                oacc[df][mf] = __builtin_amdgcn_mfma_f32_16x16x32_bf16(
                    av[df], pb.v, oacc[df][mf], 0, 0, 0);
        }
    };

    constexpr int NP = 16;                 // 32 tiles / 2
    stage(0, 0);
    stage(1, 64);
    stage(2, 128);
    stage(3, 192);
    for (int p = 0; p < NP; ++p) {
        if (p < NP - 1) { WAIT_VM(8); } else { WAIT_VM(0); }
        BARRIER;                       // tiles 2p,2p+1 landed everywhere
        compute2((2 * p) & 3, (2 * p + 1) & 3);
        if (p < NP - 2) {
            WAIT_LGKM0;
            BARRIER;                   // all reads of this pair's bufs done
            stage((2 * p) & 3, (2 * p + 4) * 64);
            stage((2 * p + 1) & 3, (2 * p + 5) * 64);
        }
    }

    float* red = (float*)smem;
    constexpr int RP = 17;
#pragma unroll
    for (int mf = 0; mf < 8; ++mf) {
        BARRIER;                       // previous chunk's reads (or loop) done
#pragma unroll
        for (int df = 0; df < 4; ++df)
#pragma unroll
            for (int r = 0; r < 4; ++r)
                red[(wave * 64 + df * 16 + quad * 4 + r) * RP + lc] =
                    oacc[df][mf][r];
        WAIT_LGKM0;
        BARRIER;                       // all partials visible
#pragma unroll
        for (int qq = 0; qq < 4; ++qq) {
            const int q = wave * 4 + qq;
            const int d = lane;
            float v = red[(0 * 64 + d) * RP + q] + red[(1 * 64 + d) * RP + q] +
                      red[(2 * 64 + d) * RP + q] + red[(3 * 64 + d) * RP + q];
            const int s = q0 + mf * 16 + q;
            attn_out[((size_t)(b * SEQ + s)) * D_MODEL + h * D_K + d] = f2bf(v);
        }
    }
}

extern "C" void kernel_launch(void* const* d_in, const int* in_sizes, int n_in,
                              void* d_out, int out_size, void* d_ws, size_t ws_size,
                              hipStream_t stream)
{
    const float* Qf   = (const float*)d_in[0];
    const float* Kf   = (const float*)d_in[1];
    const float* Vf   = (const float*)d_in[2];
    const float* Wqf  = (const float*)d_in[3];
    const float* Wqbf = (const float*)d_in[4];
    const float* Wkf  = (const float*)d_in[5];
    const float* Wkbf = (const float*)d_in[6];
    const float* Wvf  = (const float*)d_in[7];
    const float* Wvbf = (const float*)d_in[8];
    const float* Wof  = (const float*)d_in[9];
    const float* Wobf = (const float*)d_in[10];

    const size_t NM = (size_t)M_TOT * D_MODEL;
    const size_t NW = (size_t)D_MODEL * D_MODEL;
    const size_t NB = D_MODEL;

    ushort_t* p = (ushort_t*)d_ws;
    ushort_t* Wq  = p;  p += NW;
    ushort_t* Wk  = p;  p += NW;
    ushort_t* Wv  = p;  p += NW;
    ushort_t* Wo  = p;  p += NW;
    ushort_t* bq  = p;  p += NB;
    ushort_t* bk  = p;  p += NB;
    ushort_t* bvv = p;  p += NB;
    ushort_t* bo  = p;  p += NB;
    ushort_t* qn  = p;  p += NM;   // (B,H,S,DK)
    ushort_t* kn  = p;  p += NM;   // (B,H,S,DK)
    ushort_t* vT  = p;  p += NM;   // (B,H,DK,S)
    ushort_t* ao  = p;  p += NM;   // (B,S,D)

    ConvArgs ca;
    ca.src[0] = Wqf;  ca.dst[0] = Wq;  ca.n[0] = (int)NW;
    ca.src[1] = Wkf;  ca.dst[1] = Wk;  ca.n[1] = (int)NW;
    ca.src[2] = Wvf;  ca.dst[2] = Wv;  ca.n[2] = (int)NW;
    ca.src[3] = Wof;  ca.dst[3] = Wo;  ca.n[3] = (int)NW;
    ca.src[4] = Wqbf; ca.dst[4] = bq;  ca.n[4] = (int)NB;
    ca.src[5] = Wkbf; ca.dst[5] = bk;  ca.n[5] = (int)NB;
    ca.src[6] = Wvbf; ca.dst[6] = bvv; ca.n[6] = (int)NB;
    ca.src[7] = Wobf; ca.dst[7] = bo;  ca.n[7] = (int)NB;

    int cum = 0;
    ca.cum[0] = 0;
    for (int i = 0; i < 8; ++i) {
        cum += (ca.n[i] + 2047) / 2048;
        ca.cum[i + 1] = cum;
    }

    dim3 blk(256);
    convert_kernel<<<dim3((unsigned)cum), blk, 0, stream>>>(ca);

    qkv_kernel<<<dim3(768), blk, 0, stream>>>(
        Qf, Kf, Vf, Wq, Wk, Wv, bq, bk, bvv, qn, kn, vT);
    attn_kernel<<<dim3(BATCH * N_HEADS, SEQ / 128), blk, 0, stream>>>(qn, kn, vT, ao);
    wo_kernel<<<dim3(512), blk, 0, stream>>>(
        ao, Wo, bo, (float*)d_out);
}